// Round 1
// 539.591 us; speedup vs baseline: 1.0455x; 1.0455x over previous
//
#include <hip/hip_runtime.h>
#include <cstdint>
#include <cstddef>

#define N_TOK 4096
#define D_HID 2048
#define D_EXP 1024
#define NE 8
#define N_ROUTED (N_TOK * 2)
#define N_ROWS (N_ROUTED + N_TOK)   // 12288: 8192 routed slots + 4096 shared
#define MAX_BLK 56                  // >= worst-case 256-row blocks (<=55)
#define NT1 (D_HID / 32)            // 64 K-tiles (gemm1)
#define NT2 (D_EXP / 32)            // 32 K-tiles (gemm2)

typedef unsigned short u16;
typedef __bf16 bf16x8 __attribute__((ext_vector_type(8)));
typedef float f32x4 __attribute__((ext_vector_type(4)));

// ---------------- workspace layout (bytes) ----------------
constexpr size_t OFF_XB    = 0;                        // u16[N_TOK*D_HID]
constexpr size_t OFF_WG    = OFF_XB    + 16777216;     // u16[NE][D_EXP][D_HID]  (n,k)
constexpr size_t OFF_WU    = OFF_WG    + 33554432;     // u16[NE][D_EXP][D_HID]
constexpr size_t OFF_WD    = OFF_WU    + 33554432;     // u16[NE][D_HID][D_EXP]  (n,k)
constexpr size_t OFF_WSG   = OFF_WD    + 33554432;     // u16[D_EXP][D_HID]
constexpr size_t OFF_WSU   = OFF_WSG   + 4194304;      // u16[D_EXP][D_HID]
constexpr size_t OFF_WSD   = OFF_WSU   + 4194304;      // u16[D_HID][D_EXP]
constexpr size_t OFF_H     = OFF_WSD   + 4194304;      // u16[N_ROWS*D_EXP]
constexpr size_t OFF_ROWS  = OFF_H     + 25165824;     // int[N_ROWS]
constexpr size_t OFF_WSLOT = OFF_ROWS  + 49152;        // float[N_ROWS]
constexpr size_t OFF_SEG   = OFF_WSLOT + 49152;        // int[32]
constexpr size_t OFF_BLK   = OFF_SEG   + 128;          // int[192] block map
constexpr size_t OFF_TOPI  = OFF_BLK   + 768;          // int[2*N_TOK]
constexpr size_t OFF_TOPW  = OFF_TOPI  + 32768;        // float[2*N_TOK]
constexpr size_t OFF_INV   = OFF_TOPW  + 32768;        // int[2*N_TOK] token->slot
// h2 aliases Wg_t/Wu_t: dead after gemm1, stream-ordered before gemm2/combine.
constexpr size_t OFF_H2    = OFF_WG;

__device__ __forceinline__ u16 f32_to_bf16(float f) {
    union { float f; unsigned int u; } c; c.f = f;
    unsigned int u = c.u;
    return (u16)((u + 0x7FFFu + ((u >> 16) & 1u)) >> 16);
}
__device__ __forceinline__ float bf16_to_f32(u16 v) {
    union { unsigned int u; float f; } c; c.u = ((unsigned int)v) << 16;
    return c.f;
}

// async global->LDS, 16B per lane; lds dest = wave-uniform base + lane*16
__device__ __forceinline__ void gld_lds16(const u16* g, u16* l) {
    __builtin_amdgcn_global_load_lds(
        (const __attribute__((address_space(1))) void*)g,
        (__attribute__((address_space(3))) void*)l,
        16, 0, 0);
}

// ---------------- x -> bf16 ----------------
__global__ void cvt_x_kernel(const float* __restrict__ x, u16* __restrict__ xb) {
    size_t i = ((size_t)blockIdx.x * 256 + threadIdx.x) * 8;
    float4 a = *(const float4*)(x + i);
    float4 b = *(const float4*)(x + i + 4);
    union { u16 us[8]; uint4 v; } r;
    r.us[0] = f32_to_bf16(a.x); r.us[1] = f32_to_bf16(a.y);
    r.us[2] = f32_to_bf16(a.z); r.us[3] = f32_to_bf16(a.w);
    r.us[4] = f32_to_bf16(b.x); r.us[5] = f32_to_bf16(b.y);
    r.us[6] = f32_to_bf16(b.z); r.us[7] = f32_to_bf16(b.w);
    *(uint4*)(xb + i) = r.v;
}

// ---------------- weight prep: fp32 [R][C] -> bf16 [C][R], batched ----------------
__global__ void prep_gu_kernel(const float* __restrict__ Wg, const float* __restrict__ Wu,
                               const float* __restrict__ Wsg, const float* __restrict__ Wsu,
                               u16* __restrict__ Wg_t, u16* __restrict__ Wu_t,
                               u16* __restrict__ Wsg_t, u16* __restrict__ Wsu_t) {
    __shared__ float tile[64][66];
    const int z = blockIdx.z;
    const float* src; u16* dst;
    if (z < 8)        { src = Wg + (size_t)z * (D_HID * D_EXP);       dst = Wg_t + (size_t)z * (D_HID * D_EXP); }
    else if (z < 16)  { src = Wu + (size_t)(z - 8) * (D_HID * D_EXP); dst = Wu_t + (size_t)(z - 8) * (D_HID * D_EXP); }
    else if (z == 16) { src = Wsg; dst = Wsg_t; }
    else              { src = Wsu; dst = Wsu_t; }
    const int c0 = blockIdx.x * 64, r0 = blockIdx.y * 64;
    const int tid = threadIdx.x;
    const int tx = tid & 15, ty = tid >> 4;
#pragma unroll
    for (int i = 0; i < 4; i++) {
        float4 v = *(const float4*)(src + (size_t)(r0 + ty + 16 * i) * D_EXP + c0 + tx * 4);
        tile[ty + 16 * i][tx * 4 + 0] = v.x;
        tile[ty + 16 * i][tx * 4 + 1] = v.y;
        tile[ty + 16 * i][tx * 4 + 2] = v.z;
        tile[ty + 16 * i][tx * 4 + 3] = v.w;
    }
    __syncthreads();
    const int kx = tid & 7, cy = tid >> 3;
#pragma unroll
    for (int j = 0; j < 2; j++) {
        int n = cy + 32 * j;
        union { u16 us[8]; uint4 v; } r;
#pragma unroll
        for (int m = 0; m < 8; m++) r.us[m] = f32_to_bf16(tile[kx * 8 + m][n]);
        *(uint4*)(dst + (size_t)(c0 + n) * D_HID + r0 + kx * 8) = r.v;
    }
}

__global__ void prep_d_kernel(const float* __restrict__ Wd, const float* __restrict__ Wsd,
                              u16* __restrict__ Wd_t, u16* __restrict__ Wsd_t) {
    __shared__ float tile[64][66];
    const int z = blockIdx.z;
    const float* src; u16* dst;
    if (z < 8) { src = Wd + (size_t)z * (D_EXP * D_HID); dst = Wd_t + (size_t)z * (D_EXP * D_HID); }
    else       { src = Wsd; dst = Wsd_t; }
    const int c0 = blockIdx.x * 64, r0 = blockIdx.y * 64;
    const int tid = threadIdx.x;
    const int tx = tid & 15, ty = tid >> 4;
#pragma unroll
    for (int i = 0; i < 4; i++) {
        float4 v = *(const float4*)(src + (size_t)(r0 + ty + 16 * i) * D_HID + c0 + tx * 4);
        tile[ty + 16 * i][tx * 4 + 0] = v.x;
        tile[ty + 16 * i][tx * 4 + 1] = v.y;
        tile[ty + 16 * i][tx * 4 + 2] = v.z;
        tile[ty + 16 * i][tx * 4 + 3] = v.w;
    }
    __syncthreads();
    const int kx = tid & 7, cy = tid >> 3;
#pragma unroll
    for (int j = 0; j < 2; j++) {
        int n = cy + 32 * j;
        union { u16 us[8]; uint4 v; } r;
#pragma unroll
        for (int m = 0; m < 8; m++) r.us[m] = f32_to_bf16(tile[kx * 8 + m][n]);
        *(uint4*)(dst + (size_t)(c0 + n) * D_EXP + r0 + kx * 8) = r.v;
    }
}

// ---------------- router: softmax + top2 ----------------
__global__ void router_kernel(const float* __restrict__ x, const float* __restrict__ Wg,
                              int* __restrict__ topi, float* __restrict__ topw) {
    const int wave = threadIdx.x >> 6, lane = threadIdx.x & 63;
    const int t = blockIdx.x * 4 + wave;
    const float* xr = x + (size_t)t * D_HID;
    float acc[8] = {0.f, 0.f, 0.f, 0.f, 0.f, 0.f, 0.f, 0.f};
    for (int k = lane; k < D_HID; k += 64) {
        float xv = xr[k];
        float4 w0 = *(const float4*)(Wg + k * 8);
        float4 w1 = *(const float4*)(Wg + k * 8 + 4);
        acc[0] += xv * w0.x; acc[1] += xv * w0.y; acc[2] += xv * w0.z; acc[3] += xv * w0.w;
        acc[4] += xv * w1.x; acc[5] += xv * w1.y; acc[6] += xv * w1.z; acc[7] += xv * w1.w;
    }
#pragma unroll
    for (int e = 0; e < 8; e++)
#pragma unroll
        for (int off = 32; off > 0; off >>= 1)
            acc[e] += __shfl_xor(acc[e], off);
    if (lane == 0) {
        float mx = acc[0];
#pragma unroll
        for (int e = 1; e < 8; e++) mx = fmaxf(mx, acc[e]);
        float p[8], sum = 0.f;
#pragma unroll
        for (int e = 0; e < 8; e++) { p[e] = __expf(acc[e] - mx); sum += p[e]; }
        int i0 = 0; float b0 = p[0];
#pragma unroll
        for (int e = 1; e < 8; e++) if (p[e] > b0) { b0 = p[e]; i0 = e; }
        int i1 = -1; float b1 = -1.f;
#pragma unroll
        for (int e = 0; e < 8; e++) if (e != i0 && p[e] > b1) { b1 = p[e]; i1 = e; }
        float inv = 1.f / sum;
        topi[t * 2] = i0;  topi[t * 2 + 1] = i1;
        topw[t * 2] = b0 * inv; topw[t * 2 + 1] = b1 * inv;
    }
}

// ---------------- build expert segments + block map (256-row blocks) ----------------
__global__ void builder_kernel(const int* __restrict__ topi, const float* __restrict__ topw,
                               int* __restrict__ rows, float* __restrict__ wslot,
                               int* __restrict__ seg, int* __restrict__ blkmap,
                               int* __restrict__ inv) {
    __shared__ int cnt[8], offs[8];
    const int tid = threadIdx.x;
    if (tid < 8) cnt[tid] = 0;
    __syncthreads();
    for (int i = tid; i < N_TOK * 2; i += 256) atomicAdd(&cnt[topi[i]], 1);
    __syncthreads();
    if (tid == 0) {
        int run = 0;
        for (int e = 0; e < 8; e++) {
            offs[e] = run; seg[e] = run; seg[16 + e] = cnt[e]; run += cnt[e];
        }
        seg[8] = N_ROUTED; seg[16 + 8] = N_TOK;
        int nb = 0;
        for (int e = 0; e < 9; e++) {
            int L = (e < 8) ? cnt[e] : N_TOK;
            for (int rb = 0; rb * 256 < L; rb++) blkmap[nb++] = (e << 8) | rb;
        }
        seg[10] = nb;
    }
    __syncthreads();
    for (int i = tid; i < N_TOK * 2; i += 256) {
        int e = topi[i];
        int p = atomicAdd(&offs[e], 1);
        rows[p] = i >> 1;
        wslot[p] = topw[i];
        inv[i] = p;
    }
    for (int t = tid; t < N_TOK; t += 256) {
        rows[N_ROUTED + t] = t;
        wslot[N_ROUTED + t] = 1.0f;
    }
}

// =====================================================================
// GEMM1: gathered X @ {W_gate, W_up} + silu*up*w -> h (bf16)
// 8-wave, BM=256, BN=128(dual), BK=32; 4-buffer LDS ring, 2 phases/tile,
// XOR-swizzled LDS (pre-swizzled global source, linear gld_lds dest),
// counted vmcnt (8 = 2 tiles in flight), setprio around MFMA clusters.
// =====================================================================
__global__ __launch_bounds__(512, 2)
void gemm1_kernel(const u16* __restrict__ xb,
                  const u16* __restrict__ Wg_t, const u16* __restrict__ Wu_t,
                  const u16* __restrict__ Wsg_t, const u16* __restrict__ Wsu_t,
                  const int* __restrict__ rows, const float* __restrict__ wslot,
                  const int* __restrict__ seg, const int* __restrict__ blkmap,
                  u16* __restrict__ h) {
    // per buffer (16384 u16 = 32KB): A[256][32] @0, Bg[128][32] @8192, Bu @12288
    __shared__ u16 lds[4][16384];
    __shared__ int tok_s[256];
    if ((int)blockIdx.x >= seg[10]) return;
    const int code = blkmap[blockIdx.x];
    const int e = code >> 8, rb = code & 255;
    const int s = seg[e], L = seg[e + 16];
    const u16* Bg = (e < NE) ? Wg_t + (size_t)e * D_EXP * D_HID : Wsg_t;
    const u16* Bu = (e < NE) ? Wu_t + (size_t)e * D_EXP * D_HID : Wsu_t;
    const int cbase = blockIdx.y * 128;
    const int tid = threadIdx.x;
    if (tid < 256) {
        int lr = rb * 256 + tid;
        tok_s[tid] = rows[s + (lr < L ? lr : 0)];
    }
    __syncthreads();

    const int l = tid & 63, w = tid >> 6;
    // ---- staging constants: lane l stages row (w*16 + l>>2), phys chunk (l&3),
    // from global chunk (l&3)^((l>>3)&3)  [swizzle: phys p holds data chunk p^((row>>1)&3)]
    const int rl = l >> 2;
    const int cg = (l & 3) ^ ((l >> 3) & 3);
    const int rowS = w * 16 + rl;
    const u16* gA0 = xb + (size_t)tok_s[rowS] * D_HID + cg * 8;
    const u16* gA1 = xb + (size_t)tok_s[128 + rowS] * D_HID + cg * 8;
    const u16* gBg = Bg + (size_t)(cbase + rowS) * D_HID + cg * 8;
    const u16* gBu = Bu + (size_t)(cbase + rowS) * D_HID + cg * 8;
    const int wbase = w * 512;

    // ---- compute constants
    const int wm = w & 1, wn = w >> 1;           // wave tile: rows wm*128, cols wn*32
    const int ln = l & 15, quad = l >> 4;
    const int pch = (quad ^ ((ln >> 1) & 3)) * 8;       // swizzled 16B chunk within row
    const int aoff = (wm * 128 + ln) * 32 + pch;        // + m*512
    const int goff = 8192 + (wn * 32 + ln) * 32 + pch;  // + n*512; Bu at +4096

    f32x4 accg[8][2], accu[8][2];
    const f32x4 zero = {0.f, 0.f, 0.f, 0.f};
#pragma unroll
    for (int i = 0; i < 8; i++)
#pragma unroll
        for (int j = 0; j < 2; j++) { accg[i][j] = zero; accu[i][j] = zero; }

#define STAGE_A1(t) { u16* dst = &lds[(t) & 3][wbase]; \
        gld_lds16(gA0 + (t) * 32, dst); \
        gld_lds16(gA1 + (t) * 32, dst + 4096); }
#define STAGE_B1(t) { u16* dst = &lds[(t) & 3][8192 + wbase]; \
        gld_lds16(gBg + (t) * 32, dst); \
        gld_lds16(gBu + (t) * 32, dst + 4096); }

#define G1_PHASE(P, DO_STAGE) { \
        bf16x8 af[4], bgf[2], buf_[2]; \
        _Pragma("unroll") \
        for (int m = 0; m < 4; m++) af[m] = *(const bf16x8*)(bufp + aoff + ((P) * 4 + m) * 512); \
        _Pragma("unroll") \
        for (int n = 0; n < 2; n++) { \
            bgf[n]  = *(const bf16x8*)(bufp + goff + n * 512); \
            buf_[n] = *(const bf16x8*)(bufp + goff + 4096 + n * 512); } \
        DO_STAGE; \
        __builtin_amdgcn_s_barrier(); \
        asm volatile("s_waitcnt lgkmcnt(0)" ::: "memory"); \
        __builtin_amdgcn_sched_barrier(0); \
        __builtin_amdgcn_s_setprio(1); \
        _Pragma("unroll") \
        for (int n = 0; n < 2; n++) \
        _Pragma("unroll") \
        for (int m = 0; m < 4; m++) { \
            accg[(P) * 4 + m][n] = __builtin_amdgcn_mfma_f32_16x16x32_bf16(af[m], bgf[n],  accg[(P) * 4 + m][n], 0, 0, 0); \
            accu[(P) * 4 + m][n] = __builtin_amdgcn_mfma_f32_16x16x32_bf16(af[m], buf_[n], accu[(P) * 4 + m][n], 0, 0, 0); } \
        __builtin_amdgcn_s_setprio(0); \
    }

    // prologue: 3 tiles in flight
    STAGE_A1(0); STAGE_B1(0);
    STAGE_A1(1); STAGE_B1(1);
    STAGE_A1(2); STAGE_B1(2);

#pragma unroll 1
    for (int t = 0; t < NT1; ++t) {
        // wait own tile-t loads (tiles t+1,t+2 = 8 loads may remain in flight)
        if (t < NT1 - 2)       asm volatile("s_waitcnt vmcnt(8)" ::: "memory");
        else if (t == NT1 - 2) asm volatile("s_waitcnt vmcnt(4)" ::: "memory");
        else                   asm volatile("s_waitcnt vmcnt(0)" ::: "memory");
        __builtin_amdgcn_s_barrier();           // all waves' tile-t landed; buf[(t+3)&3] free
        __builtin_amdgcn_sched_barrier(0);      // nothing crosses the tile boundary
        const u16* bufp = &lds[t & 3][0];
        G1_PHASE(0, if (t + 3 < NT1) STAGE_A1(t + 3));
        __builtin_amdgcn_s_barrier();
        G1_PHASE(1, if (t + 3 < NT1) STAGE_B1(t + 3));
    }
#undef G1_PHASE
#undef STAGE_A1
#undef STAGE_B1

    // epilogue: silu(g)*u*w -> h
#pragma unroll
    for (int m = 0; m < 8; m++) {
#pragma unroll
        for (int r = 0; r < 4; r++) {
            int lrow = rb * 256 + wm * 128 + m * 16 + quad * 4 + r;
            if (lrow >= L) continue;
            int pos = s + lrow;
            float wgt = wslot[pos];
#pragma unroll
            for (int n = 0; n < 2; n++) {
                float g = accg[m][n][r];
                float u = accu[m][n][r];
                float hv = (g / (1.f + __expf(-g))) * u * wgt;
                h[(size_t)pos * D_EXP + cbase + wn * 32 + n * 16 + ln] = f32_to_bf16(hv);
            }
        }
    }
}

// =====================================================================
// GEMM2: h @ W_down -> h2 (bf16 per-slot), same 8-wave pipelined schedule.
// BM=256, BN=256, BK=32; buffer: A[256][32] @0, B[256][32] @8192.
// =====================================================================
__global__ __launch_bounds__(512, 2)
void gemm2_kernel(const u16* __restrict__ h,
                  const u16* __restrict__ Wd_t, const u16* __restrict__ Wsd_t,
                  const int* __restrict__ seg, const int* __restrict__ blkmap,
                  u16* __restrict__ h2) {
    __shared__ u16 lds[4][16384];
    if ((int)blockIdx.x >= seg[10]) return;
    const int code = blkmap[blockIdx.x];
    const int e = code >> 8, rb = code & 255;
    const int s = seg[e], L = seg[e + 16];
    const u16* B = (e < NE) ? Wd_t + (size_t)e * D_HID * D_EXP : Wsd_t;  // [N=2048][K=1024]
    const int cbase = blockIdx.y * 256;
    const int tid = threadIdx.x;

    const int l = tid & 63, w = tid >> 6;
    const int rl = l >> 2;
    const int cg = (l & 3) ^ ((l >> 3) & 3);
    const int rowS = w * 16 + rl;
    const u16* gA0 = h + (size_t)(s + rb * 256 + rowS) * D_EXP + cg * 8;
    const u16* gA1 = gA0 + (size_t)128 * D_EXP;
    const u16* gB0 = B + (size_t)(cbase + rowS) * D_EXP + cg * 8;
    const u16* gB1 = gB0 + (size_t)128 * D_EXP;
    const int wbase = w * 512;

    const int wm = w & 1, wn = w >> 1;           // wave tile: rows wm*128, cols wn*64
    const int ln = l & 15, quad = l >> 4;
    const int pch = (quad ^ ((ln >> 1) & 3)) * 8;
    const int aoff = (wm * 128 + ln) * 32 + pch;         // + m*512
    const int boff = 8192 + (wn * 64 + ln) * 32 + pch;   // + n*512

    f32x4 acc[8][4];
    const f32x4 zero = {0.f, 0.f, 0.f, 0.f};
#pragma unroll
    for (int i = 0; i < 8; i++)
#pragma unroll
        for (int j = 0; j < 4; j++) acc[i][j] = zero;

#define STAGE_A2(t) { u16* dst = &lds[(t) & 3][wbase]; \
        gld_lds16(gA0 + (t) * 32, dst); \
        gld_lds16(gA1 + (t) * 32, dst + 4096); }
#define STAGE_B2(t) { u16* dst = &lds[(t) & 3][8192 + wbase]; \
        gld_lds16(gB0 + (t) * 32, dst); \
        gld_lds16(gB1 + (t) * 32, dst + 4096); }

#define G2_PHASE(P, DO_STAGE) { \
        bf16x8 af[4], bf[4]; \
        _Pragma("unroll") \
        for (int m = 0; m < 4; m++) af[m] = *(const bf16x8*)(bufp + aoff + ((P) * 4 + m) * 512); \
        _Pragma("unroll") \
        for (int n = 0; n < 4; n++) bf[n] = *(const bf16x8*)(bufp + boff + n * 512); \
        DO_STAGE; \
        __builtin_amdgcn_s_barrier(); \
        asm volatile("s_waitcnt lgkmcnt(0)" ::: "memory"); \
        __builtin_amdgcn_sched_barrier(0); \
        __builtin_amdgcn_s_setprio(1); \
        _Pragma("unroll") \
        for (int n = 0; n < 4; n++) \
        _Pragma("unroll") \
        for (int m = 0; m < 4; m++) \
            acc[(P) * 4 + m][n] = __builtin_amdgcn_mfma_f32_16x16x32_bf16(af[m], bf[n], acc[(P) * 4 + m][n], 0, 0, 0); \
        __builtin_amdgcn_s_setprio(0); \
    }

    STAGE_A2(0); STAGE_B2(0);
    STAGE_A2(1); STAGE_B2(1);
    STAGE_A2(2); STAGE_B2(2);

#pragma unroll 1
    for (int t = 0; t < NT2; ++t) {
        if (t < NT2 - 2)       asm volatile("s_waitcnt vmcnt(8)" ::: "memory");
        else if (t == NT2 - 2) asm volatile("s_waitcnt vmcnt(4)" ::: "memory");
        else                   asm volatile("s_waitcnt vmcnt(0)" ::: "memory");
        __builtin_amdgcn_s_barrier();
        __builtin_amdgcn_sched_barrier(0);
        const u16* bufp = &lds[t & 3][0];
        G2_PHASE(0, if (t + 3 < NT2) STAGE_A2(t + 3));
        __builtin_amdgcn_s_barrier();
        G2_PHASE(1, if (t + 3 < NT2) STAGE_B2(t + 3));
    }
#undef G2_PHASE
#undef STAGE_A2
#undef STAGE_B2

#pragma unroll
    for (int m = 0; m < 8; m++) {
#pragma unroll
        for (int r = 0; r < 4; r++) {
            int lrow = rb * 256 + wm * 128 + m * 16 + quad * 4 + r;
            if (lrow >= L) continue;
            size_t slot = (size_t)(s + lrow);
#pragma unroll
            for (int n = 0; n < 4; n++) {
                h2[slot * D_HID + cbase + wn * 64 + n * 16 + ln] = f32_to_bf16(acc[m][n][r]);
            }
        }
    }
}

// ---------------- combine: out[t] = h2[slot0] + h2[slot1] + h2[shared] ----------------
__global__ void combine_kernel(const u16* __restrict__ h2, const int* __restrict__ inv,
                               float* __restrict__ out) {
    const int t = blockIdx.x;
    const int d = threadIdx.x * 8;
    const size_t r0 = (size_t)inv[t * 2] * D_HID + d;
    const size_t r1 = (size_t)inv[t * 2 + 1] * D_HID + d;
    const size_t r2 = (size_t)(N_ROUTED + t) * D_HID + d;
    union { uint4 v; u16 us[8]; } a, b, c;
    a.v = *(const uint4*)(h2 + r0);
    b.v = *(const uint4*)(h2 + r1);
    c.v = *(const uint4*)(h2 + r2);
    float4 lo, hi;
    lo.x = bf16_to_f32(a.us[0]) + bf16_to_f32(b.us[0]) + bf16_to_f32(c.us[0]);
    lo.y = bf16_to_f32(a.us[1]) + bf16_to_f32(b.us[1]) + bf16_to_f32(c.us[1]);
    lo.z = bf16_to_f32(a.us[2]) + bf16_to_f32(b.us[2]) + bf16_to_f32(c.us[2]);
    lo.w = bf16_to_f32(a.us[3]) + bf16_to_f32(b.us[3]) + bf16_to_f32(c.us[3]);
    hi.x = bf16_to_f32(a.us[4]) + bf16_to_f32(b.us[4]) + bf16_to_f32(c.us[4]);
    hi.y = bf16_to_f32(a.us[5]) + bf16_to_f32(b.us[5]) + bf16_to_f32(c.us[5]);
    hi.z = bf16_to_f32(a.us[6]) + bf16_to_f32(b.us[6]) + bf16_to_f32(c.us[6]);
    hi.w = bf16_to_f32(a.us[7]) + bf16_to_f32(b.us[7]) + bf16_to_f32(c.us[7]);
    float* o = out + (size_t)t * D_HID + d;
    *(float4*)o = lo;
    *(float4*)(o + 4) = hi;
}

// ---------------- launch ----------------
extern "C" void kernel_launch(void* const* d_in, const int* in_sizes, int n_in,
                              void* d_out, int out_size, void* d_ws, size_t ws_size,
                              hipStream_t stream) {
    const float* x       = (const float*)d_in[0];
    const float* W_g     = (const float*)d_in[1];
    const float* W_gate  = (const float*)d_in[2];
    const float* W_up    = (const float*)d_in[3];
    const float* W_down  = (const float*)d_in[4];
    const float* Ws_gate = (const float*)d_in[5];
    const float* Ws_up   = (const float*)d_in[6];
    const float* Ws_down = (const float*)d_in[7];
    float* out = (float*)d_out;
    char* ws = (char*)d_ws;

    u16*   xb    = (u16*)(ws + OFF_XB);
    u16*   Wg_t  = (u16*)(ws + OFF_WG);
    u16*   Wu_t  = (u16*)(ws + OFF_WU);
    u16*   Wd_t  = (u16*)(ws + OFF_WD);
    u16*   Wsg_t = (u16*)(ws + OFF_WSG);
    u16*   Wsu_t = (u16*)(ws + OFF_WSU);
    u16*   Wsd_t = (u16*)(ws + OFF_WSD);
    u16*   h     = (u16*)(ws + OFF_H);
    u16*   h2    = (u16*)(ws + OFF_H2);
    int*   rows  = (int*)(ws + OFF_ROWS);
    float* wslot = (float*)(ws + OFF_WSLOT);
    int*   seg   = (int*)(ws + OFF_SEG);
    int*   blkmap= (int*)(ws + OFF_BLK);
    int*   topi  = (int*)(ws + OFF_TOPI);
    float* topw  = (float*)(ws + OFF_TOPW);
    int*   inv   = (int*)(ws + OFF_INV);

    cvt_x_kernel<<<dim3((N_TOK * D_HID) / (256 * 8)), dim3(256), 0, stream>>>(x, xb);
    prep_gu_kernel<<<dim3(D_EXP / 64, D_HID / 64, 18), dim3(256), 0, stream>>>(
        W_gate, W_up, Ws_gate, Ws_up, Wg_t, Wu_t, Wsg_t, Wsu_t);
    prep_d_kernel<<<dim3(D_HID / 64, D_EXP / 64, 9), dim3(256), 0, stream>>>(
        W_down, Ws_down, Wd_t, Wsd_t);

    router_kernel<<<dim3(N_TOK / 4), dim3(256), 0, stream>>>(x, W_g, topi, topw);
    builder_kernel<<<dim3(1), dim3(256), 0, stream>>>(topi, topw, rows, wslot, seg, blkmap, inv);

    gemm1_kernel<<<dim3(MAX_BLK, D_EXP / 128), dim3(512), 0, stream>>>(
        xb, Wg_t, Wu_t, Wsg_t, Wsu_t, rows, wslot, seg, blkmap, h);
    gemm2_kernel<<<dim3(MAX_BLK, D_HID / 256), dim3(512), 0, stream>>>(
        h, Wd_t, Wsd_t, seg, blkmap, h2);
    combine_kernel<<<dim3(N_TOK), dim3(256), 0, stream>>>(h2, inv, out);
}

// Round 2
// 527.674 us; speedup vs baseline: 1.0691x; 1.0226x over previous
//
#include <hip/hip_runtime.h>
#include <cstdint>
#include <cstddef>

#define N_TOK 4096
#define D_HID 2048
#define D_EXP 1024
#define NE 8
#define N_ROUTED (N_TOK * 2)
#define N_ROWS (N_ROUTED + N_TOK)   // 12288: 8192 routed slots + 4096 shared
#define MAX_BLK 56                  // >= worst-case 256-row blocks (<=55)
#define NT1 (D_HID / 32)            // 64 K-tiles (gemm1)
#define NT2 (D_EXP / 32)            // 32 K-tiles (gemm2)

typedef unsigned short u16;
typedef __bf16 bf16x8 __attribute__((ext_vector_type(8)));
typedef float f32x4 __attribute__((ext_vector_type(4)));

// ---------------- workspace layout (bytes) ----------------
constexpr size_t OFF_XB    = 0;                        // u16[N_TOK*D_HID]
constexpr size_t OFF_WG    = OFF_XB    + 16777216;     // u16[NE][D_EXP][D_HID]  (n,k)
constexpr size_t OFF_WU    = OFF_WG    + 33554432;     // u16[NE][D_EXP][D_HID]
constexpr size_t OFF_WD    = OFF_WU    + 33554432;     // u16[NE][D_HID][D_EXP]  (n,k)
constexpr size_t OFF_WSG   = OFF_WD    + 33554432;     // u16[D_EXP][D_HID]
constexpr size_t OFF_WSU   = OFF_WSG   + 4194304;      // u16[D_EXP][D_HID]
constexpr size_t OFF_WSD   = OFF_WSU   + 4194304;      // u16[D_HID][D_EXP]
constexpr size_t OFF_H     = OFF_WSD   + 4194304;      // u16[N_ROWS*D_EXP]
constexpr size_t OFF_ROWS  = OFF_H     + 25165824;     // int[N_ROWS]
constexpr size_t OFF_WSLOT = OFF_ROWS  + 49152;        // float[N_ROWS]
constexpr size_t OFF_SEG   = OFF_WSLOT + 49152;        // int[32]
constexpr size_t OFF_BLK   = OFF_SEG   + 128;          // int[192] block map
constexpr size_t OFF_TOPI  = OFF_BLK   + 768;          // int[2*N_TOK]
constexpr size_t OFF_TOPW  = OFF_TOPI  + 32768;        // float[2*N_TOK]
constexpr size_t OFF_INV   = OFF_TOPW  + 32768;        // int[2*N_TOK] token->slot
// h2 aliases Wg_t/Wu_t: dead after gemm1, stream-ordered before gemm2/combine.
constexpr size_t OFF_H2    = OFF_WG;

__device__ __forceinline__ u16 f32_to_bf16(float f) {
    union { float f; unsigned int u; } c; c.f = f;
    unsigned int u = c.u;
    return (u16)((u + 0x7FFFu + ((u >> 16) & 1u)) >> 16);
}
__device__ __forceinline__ float bf16_to_f32(u16 v) {
    union { unsigned int u; float f; } c; c.u = ((unsigned int)v) << 16;
    return c.f;
}

// async global->LDS, 16B per lane; lds dest = wave-uniform base + lane*16
__device__ __forceinline__ void gld_lds16(const u16* g, u16* l) {
    __builtin_amdgcn_global_load_lds(
        (const __attribute__((address_space(1))) void*)g,
        (__attribute__((address_space(3))) void*)l,
        16, 0, 0);
}

// ---------------- x -> bf16 ----------------
__global__ void cvt_x_kernel(const float* __restrict__ x, u16* __restrict__ xb) {
    size_t i = ((size_t)blockIdx.x * 256 + threadIdx.x) * 8;
    float4 a = *(const float4*)(x + i);
    float4 b = *(const float4*)(x + i + 4);
    union { u16 us[8]; uint4 v; } r;
    r.us[0] = f32_to_bf16(a.x); r.us[1] = f32_to_bf16(a.y);
    r.us[2] = f32_to_bf16(a.z); r.us[3] = f32_to_bf16(a.w);
    r.us[4] = f32_to_bf16(b.x); r.us[5] = f32_to_bf16(b.y);
    r.us[6] = f32_to_bf16(b.z); r.us[7] = f32_to_bf16(b.w);
    *(uint4*)(xb + i) = r.v;
}

// ---------------- weight prep: fp32 [R][C] -> bf16 [C][R], batched ----------------
__global__ void prep_gu_kernel(const float* __restrict__ Wg, const float* __restrict__ Wu,
                               const float* __restrict__ Wsg, const float* __restrict__ Wsu,
                               u16* __restrict__ Wg_t, u16* __restrict__ Wu_t,
                               u16* __restrict__ Wsg_t, u16* __restrict__ Wsu_t) {
    __shared__ float tile[64][66];
    const int z = blockIdx.z;
    const float* src; u16* dst;
    if (z < 8)        { src = Wg + (size_t)z * (D_HID * D_EXP);       dst = Wg_t + (size_t)z * (D_HID * D_EXP); }
    else if (z < 16)  { src = Wu + (size_t)(z - 8) * (D_HID * D_EXP); dst = Wu_t + (size_t)(z - 8) * (D_HID * D_EXP); }
    else if (z == 16) { src = Wsg; dst = Wsg_t; }
    else              { src = Wsu; dst = Wsu_t; }
    const int c0 = blockIdx.x * 64, r0 = blockIdx.y * 64;
    const int tid = threadIdx.x;
    const int tx = tid & 15, ty = tid >> 4;
#pragma unroll
    for (int i = 0; i < 4; i++) {
        float4 v = *(const float4*)(src + (size_t)(r0 + ty + 16 * i) * D_EXP + c0 + tx * 4);
        tile[ty + 16 * i][tx * 4 + 0] = v.x;
        tile[ty + 16 * i][tx * 4 + 1] = v.y;
        tile[ty + 16 * i][tx * 4 + 2] = v.z;
        tile[ty + 16 * i][tx * 4 + 3] = v.w;
    }
    __syncthreads();
    const int kx = tid & 7, cy = tid >> 3;
#pragma unroll
    for (int j = 0; j < 2; j++) {
        int n = cy + 32 * j;
        union { u16 us[8]; uint4 v; } r;
#pragma unroll
        for (int m = 0; m < 8; m++) r.us[m] = f32_to_bf16(tile[kx * 8 + m][n]);
        *(uint4*)(dst + (size_t)(c0 + n) * D_HID + r0 + kx * 8) = r.v;
    }
}

__global__ void prep_d_kernel(const float* __restrict__ Wd, const float* __restrict__ Wsd,
                              u16* __restrict__ Wd_t, u16* __restrict__ Wsd_t) {
    __shared__ float tile[64][66];
    const int z = blockIdx.z;
    const float* src; u16* dst;
    if (z < 8) { src = Wd + (size_t)z * (D_EXP * D_HID); dst = Wd_t + (size_t)z * (D_EXP * D_HID); }
    else       { src = Wsd; dst = Wsd_t; }
    const int c0 = blockIdx.x * 64, r0 = blockIdx.y * 64;
    const int tid = threadIdx.x;
    const int tx = tid & 15, ty = tid >> 4;
#pragma unroll
    for (int i = 0; i < 4; i++) {
        float4 v = *(const float4*)(src + (size_t)(r0 + ty + 16 * i) * D_HID + c0 + tx * 4);
        tile[ty + 16 * i][tx * 4 + 0] = v.x;
        tile[ty + 16 * i][tx * 4 + 1] = v.y;
        tile[ty + 16 * i][tx * 4 + 2] = v.z;
        tile[ty + 16 * i][tx * 4 + 3] = v.w;
    }
    __syncthreads();
    const int kx = tid & 7, cy = tid >> 3;
#pragma unroll
    for (int j = 0; j < 2; j++) {
        int n = cy + 32 * j;
        union { u16 us[8]; uint4 v; } r;
#pragma unroll
        for (int m = 0; m < 8; m++) r.us[m] = f32_to_bf16(tile[kx * 8 + m][n]);
        *(uint4*)(dst + (size_t)(c0 + n) * D_EXP + r0 + kx * 8) = r.v;
    }
}

// ---------------- router: softmax + top2 ----------------
__global__ void router_kernel(const float* __restrict__ x, const float* __restrict__ Wg,
                              int* __restrict__ topi, float* __restrict__ topw) {
    const int wave = threadIdx.x >> 6, lane = threadIdx.x & 63;
    const int t = blockIdx.x * 4 + wave;
    const float* xr = x + (size_t)t * D_HID;
    float acc[8] = {0.f, 0.f, 0.f, 0.f, 0.f, 0.f, 0.f, 0.f};
    for (int k = lane; k < D_HID; k += 64) {
        float xv = xr[k];
        float4 w0 = *(const float4*)(Wg + k * 8);
        float4 w1 = *(const float4*)(Wg + k * 8 + 4);
        acc[0] += xv * w0.x; acc[1] += xv * w0.y; acc[2] += xv * w0.z; acc[3] += xv * w0.w;
        acc[4] += xv * w1.x; acc[5] += xv * w1.y; acc[6] += xv * w1.z; acc[7] += xv * w1.w;
    }
#pragma unroll
    for (int e = 0; e < 8; e++)
#pragma unroll
        for (int off = 32; off > 0; off >>= 1)
            acc[e] += __shfl_xor(acc[e], off);
    if (lane == 0) {
        float mx = acc[0];
#pragma unroll
        for (int e = 1; e < 8; e++) mx = fmaxf(mx, acc[e]);
        float p[8], sum = 0.f;
#pragma unroll
        for (int e = 0; e < 8; e++) { p[e] = __expf(acc[e] - mx); sum += p[e]; }
        int i0 = 0; float b0 = p[0];
#pragma unroll
        for (int e = 1; e < 8; e++) if (p[e] > b0) { b0 = p[e]; i0 = e; }
        int i1 = -1; float b1 = -1.f;
#pragma unroll
        for (int e = 0; e < 8; e++) if (e != i0 && p[e] > b1) { b1 = p[e]; i1 = e; }
        float inv = 1.f / sum;
        topi[t * 2] = i0;  topi[t * 2 + 1] = i1;
        topw[t * 2] = b0 * inv; topw[t * 2 + 1] = b1 * inv;
    }
}

// ---------------- build expert segments + block map (256-row blocks) ----------------
__global__ void builder_kernel(const int* __restrict__ topi, const float* __restrict__ topw,
                               int* __restrict__ rows, float* __restrict__ wslot,
                               int* __restrict__ seg, int* __restrict__ blkmap,
                               int* __restrict__ inv) {
    __shared__ int cnt[8], offs[8];
    const int tid = threadIdx.x;
    if (tid < 8) cnt[tid] = 0;
    __syncthreads();
    for (int i = tid; i < N_TOK * 2; i += 256) atomicAdd(&cnt[topi[i]], 1);
    __syncthreads();
    if (tid == 0) {
        int run = 0;
        for (int e = 0; e < 8; e++) {
            offs[e] = run; seg[e] = run; seg[16 + e] = cnt[e]; run += cnt[e];
        }
        seg[8] = N_ROUTED; seg[16 + 8] = N_TOK;
        int nb = 0;
        for (int e = 0; e < 9; e++) {
            int L = (e < 8) ? cnt[e] : N_TOK;
            for (int rb = 0; rb * 256 < L; rb++) blkmap[nb++] = (e << 8) | rb;
        }
        seg[10] = nb;
    }
    __syncthreads();
    for (int i = tid; i < N_TOK * 2; i += 256) {
        int e = topi[i];
        int p = atomicAdd(&offs[e], 1);
        rows[p] = i >> 1;
        wslot[p] = topw[i];
        inv[i] = p;
    }
    for (int t = tid; t < N_TOK; t += 256) {
        rows[N_ROUTED + t] = t;
        wslot[N_ROUTED + t] = 1.0f;
    }
}

// =====================================================================
// GEMM1: gathered X @ {W_gate, W_up} + silu*up*w -> h (bf16)
// 8-wave, BM=256, BN=128(dual), BK=32; 4-buffer LDS ring,
// XOR-swizzled LDS, counted vmcnt (8 = 2 tiles in flight), setprio.
// R2: B-frags read once/tile (16->12 ds_reads), mid-tile barrier dropped,
//     1-D grid with iy=bid&7 XCD decode (B panels L2-local per XCD).
// =====================================================================
__global__ __launch_bounds__(512, 2)
void gemm1_kernel(const u16* __restrict__ xb,
                  const u16* __restrict__ Wg_t, const u16* __restrict__ Wu_t,
                  const u16* __restrict__ Wsg_t, const u16* __restrict__ Wsu_t,
                  const int* __restrict__ rows, const float* __restrict__ wslot,
                  const int* __restrict__ seg, const int* __restrict__ blkmap,
                  u16* __restrict__ h) {
    // per buffer (16384 u16 = 32KB): A[256][32] @0, Bg[128][32] @8192, Bu @12288
    __shared__ u16 lds[4][16384];
    __shared__ int tok_s[256];
    const int f = blockIdx.x;
    const int iy = f & 7, ix = f >> 3;   // iy -> XCD (round-robin dispatch)
    if (ix >= seg[10]) return;
    const int code = blkmap[ix];
    const int e = code >> 8, rb = code & 255;
    const int s = seg[e], L = seg[e + 16];
    const u16* Bg = (e < NE) ? Wg_t + (size_t)e * D_EXP * D_HID : Wsg_t;
    const u16* Bu = (e < NE) ? Wu_t + (size_t)e * D_EXP * D_HID : Wsu_t;
    const int cbase = iy * 128;
    const int tid = threadIdx.x;
    if (tid < 256) {
        int lr = rb * 256 + tid;
        tok_s[tid] = rows[s + (lr < L ? lr : 0)];
    }
    __syncthreads();

    const int l = tid & 63, w = tid >> 6;
    // staging: lane l stages row (w*16 + l>>2), phys chunk (l&3),
    // from global chunk (l&3)^((l>>3)&3)  [swizzle: phys p holds chunk p^((row>>1)&3)]
    const int rl = l >> 2;
    const int cg = (l & 3) ^ ((l >> 3) & 3);
    const int rowS = w * 16 + rl;
    const u16* gA0 = xb + (size_t)tok_s[rowS] * D_HID + cg * 8;
    const u16* gA1 = xb + (size_t)tok_s[128 + rowS] * D_HID + cg * 8;
    const u16* gBg = Bg + (size_t)(cbase + rowS) * D_HID + cg * 8;
    const u16* gBu = Bu + (size_t)(cbase + rowS) * D_HID + cg * 8;
    const int wbase = w * 512;

    const int wm = w & 1, wn = w >> 1;           // wave tile: rows wm*128, cols wn*32
    const int ln = l & 15, quad = l >> 4;
    const int pch = (quad ^ ((ln >> 1) & 3)) * 8;       // swizzled 16B chunk within row
    const int aoff = (wm * 128 + ln) * 32 + pch;        // + m*512
    const int goff = 8192 + (wn * 32 + ln) * 32 + pch;  // + n*512; Bu at +4096

    f32x4 accg[8][2], accu[8][2];
    const f32x4 zero = {0.f, 0.f, 0.f, 0.f};
#pragma unroll
    for (int i = 0; i < 8; i++)
#pragma unroll
        for (int j = 0; j < 2; j++) { accg[i][j] = zero; accu[i][j] = zero; }

#define STAGE_A1(t) { u16* dst = &lds[(t) & 3][wbase]; \
        gld_lds16(gA0 + (t) * 32, dst); \
        gld_lds16(gA1 + (t) * 32, dst + 4096); }
#define STAGE_B1(t) { u16* dst = &lds[(t) & 3][8192 + wbase]; \
        gld_lds16(gBg + (t) * 32, dst); \
        gld_lds16(gBu + (t) * 32, dst + 4096); }

    // prologue: 3 tiles in flight
    STAGE_A1(0); STAGE_B1(0);
    STAGE_A1(1); STAGE_B1(1);
    STAGE_A1(2); STAGE_B1(2);

#pragma unroll 1
    for (int t = 0; t < NT1; ++t) {
        // wait own tile-t loads (tiles t+1,t+2 = 8 loads may remain in flight)
        if (t < NT1 - 2)       asm volatile("s_waitcnt vmcnt(8)" ::: "memory");
        else if (t == NT1 - 2) asm volatile("s_waitcnt vmcnt(4)" ::: "memory");
        else                   asm volatile("s_waitcnt vmcnt(0)" ::: "memory");
        __builtin_amdgcn_s_barrier();           // all waves' tile-t landed; buf[(t+3)&3] free
        __builtin_amdgcn_sched_barrier(0);
        const u16* bufp = &lds[t & 3][0];
        bf16x8 af[4], bg[2], bu[2];
        // ---- P0: m=0..3, B read once for whole tile ----
#pragma unroll
        for (int m = 0; m < 4; m++) af[m] = *(const bf16x8*)(bufp + aoff + m * 512);
#pragma unroll
        for (int n = 0; n < 2; n++) {
            bg[n] = *(const bf16x8*)(bufp + goff + n * 512);
            bu[n] = *(const bf16x8*)(bufp + goff + 4096 + n * 512);
        }
        if (t + 3 < NT1) STAGE_A1(t + 3);
        __builtin_amdgcn_s_barrier();
        asm volatile("s_waitcnt lgkmcnt(0)" ::: "memory");
        __builtin_amdgcn_sched_barrier(0);
        __builtin_amdgcn_s_setprio(1);
#pragma unroll
        for (int n = 0; n < 2; n++)
#pragma unroll
            for (int m = 0; m < 4; m++) {
                accg[m][n] = __builtin_amdgcn_mfma_f32_16x16x32_bf16(af[m], bg[n], accg[m][n], 0, 0, 0);
                accu[m][n] = __builtin_amdgcn_mfma_f32_16x16x32_bf16(af[m], bu[n], accu[m][n], 0, 0, 0);
            }
        __builtin_amdgcn_s_setprio(0);
        // ---- P1: m=4..7, B kept in regs ----
#pragma unroll
        for (int m = 0; m < 4; m++) af[m] = *(const bf16x8*)(bufp + aoff + (4 + m) * 512);
        if (t + 3 < NT1) STAGE_B1(t + 3);
        __builtin_amdgcn_s_barrier();
        asm volatile("s_waitcnt lgkmcnt(0)" ::: "memory");
        __builtin_amdgcn_sched_barrier(0);
        __builtin_amdgcn_s_setprio(1);
#pragma unroll
        for (int n = 0; n < 2; n++)
#pragma unroll
            for (int m = 0; m < 4; m++) {
                accg[4 + m][n] = __builtin_amdgcn_mfma_f32_16x16x32_bf16(af[m], bg[n], accg[4 + m][n], 0, 0, 0);
                accu[4 + m][n] = __builtin_amdgcn_mfma_f32_16x16x32_bf16(af[m], bu[n], accu[4 + m][n], 0, 0, 0);
            }
        __builtin_amdgcn_s_setprio(0);
    }
#undef STAGE_A1
#undef STAGE_B1

    // epilogue: silu(g)*u*w -> h
#pragma unroll
    for (int m = 0; m < 8; m++) {
#pragma unroll
        for (int r = 0; r < 4; r++) {
            int lrow = rb * 256 + wm * 128 + m * 16 + quad * 4 + r;
            if (lrow >= L) continue;
            int pos = s + lrow;
            float wgt = wslot[pos];
#pragma unroll
            for (int n = 0; n < 2; n++) {
                float g = accg[m][n][r];
                float u = accu[m][n][r];
                float hv = (g / (1.f + __expf(-g))) * u * wgt;
                h[(size_t)pos * D_EXP + cbase + wn * 32 + n * 16 + ln] = f32_to_bf16(hv);
            }
        }
    }
}

// =====================================================================
// GEMM2: h @ W_down -> h2 (bf16 per-slot), same pipelined schedule.
// BM=256, BN=256, BK=32; buffer: A[256][32] @0, B[256][32] @8192.
// =====================================================================
__global__ __launch_bounds__(512, 2)
void gemm2_kernel(const u16* __restrict__ h,
                  const u16* __restrict__ Wd_t, const u16* __restrict__ Wsd_t,
                  const int* __restrict__ seg, const int* __restrict__ blkmap,
                  u16* __restrict__ h2) {
    __shared__ u16 lds[4][16384];
    const int f = blockIdx.x;
    const int iy = f & 7, ix = f >> 3;   // iy -> XCD
    if (ix >= seg[10]) return;
    const int code = blkmap[ix];
    const int e = code >> 8, rb = code & 255;
    const int s = seg[e], L = seg[e + 16];
    const u16* B = (e < NE) ? Wd_t + (size_t)e * D_HID * D_EXP : Wsd_t;  // [N=2048][K=1024]
    const int cbase = iy * 256;
    const int tid = threadIdx.x;

    const int l = tid & 63, w = tid >> 6;
    const int rl = l >> 2;
    const int cg = (l & 3) ^ ((l >> 3) & 3);
    const int rowS = w * 16 + rl;
    const u16* gA0 = h + (size_t)(s + rb * 256 + rowS) * D_EXP + cg * 8;
    const u16* gA1 = gA0 + (size_t)128 * D_EXP;
    const u16* gB0 = B + (size_t)(cbase + rowS) * D_EXP + cg * 8;
    const u16* gB1 = gB0 + (size_t)128 * D_EXP;
    const int wbase = w * 512;

    const int wm = w & 1, wn = w >> 1;           // wave tile: rows wm*128, cols wn*64
    const int ln = l & 15, quad = l >> 4;
    const int pch = (quad ^ ((ln >> 1) & 3)) * 8;
    const int aoff = (wm * 128 + ln) * 32 + pch;         // + m*512
    const int boff = 8192 + (wn * 64 + ln) * 32 + pch;   // + n*512

    f32x4 acc[8][4];
    const f32x4 zero = {0.f, 0.f, 0.f, 0.f};
#pragma unroll
    for (int i = 0; i < 8; i++)
#pragma unroll
        for (int j = 0; j < 4; j++) acc[i][j] = zero;

#define STAGE_A2(t) { u16* dst = &lds[(t) & 3][wbase]; \
        gld_lds16(gA0 + (t) * 32, dst); \
        gld_lds16(gA1 + (t) * 32, dst + 4096); }
#define STAGE_B2(t) { u16* dst = &lds[(t) & 3][8192 + wbase]; \
        gld_lds16(gB0 + (t) * 32, dst); \
        gld_lds16(gB1 + (t) * 32, dst + 4096); }

    STAGE_A2(0); STAGE_B2(0);
    STAGE_A2(1); STAGE_B2(1);
    STAGE_A2(2); STAGE_B2(2);

#pragma unroll 1
    for (int t = 0; t < NT2; ++t) {
        if (t < NT2 - 2)       asm volatile("s_waitcnt vmcnt(8)" ::: "memory");
        else if (t == NT2 - 2) asm volatile("s_waitcnt vmcnt(4)" ::: "memory");
        else                   asm volatile("s_waitcnt vmcnt(0)" ::: "memory");
        __builtin_amdgcn_s_barrier();
        __builtin_amdgcn_sched_barrier(0);
        const u16* bufp = &lds[t & 3][0];
        bf16x8 af[4], bf[4];
        // ---- P0: m=0..3, B read once for whole tile ----
#pragma unroll
        for (int m = 0; m < 4; m++) af[m] = *(const bf16x8*)(bufp + aoff + m * 512);
#pragma unroll
        for (int n = 0; n < 4; n++) bf[n] = *(const bf16x8*)(bufp + boff + n * 512);
        if (t + 3 < NT2) STAGE_A2(t + 3);
        __builtin_amdgcn_s_barrier();
        asm volatile("s_waitcnt lgkmcnt(0)" ::: "memory");
        __builtin_amdgcn_sched_barrier(0);
        __builtin_amdgcn_s_setprio(1);
#pragma unroll
        for (int n = 0; n < 4; n++)
#pragma unroll
            for (int m = 0; m < 4; m++)
                acc[m][n] = __builtin_amdgcn_mfma_f32_16x16x32_bf16(af[m], bf[n], acc[m][n], 0, 0, 0);
        __builtin_amdgcn_s_setprio(0);
        // ---- P1: m=4..7 ----
#pragma unroll
        for (int m = 0; m < 4; m++) af[m] = *(const bf16x8*)(bufp + aoff + (4 + m) * 512);
        if (t + 3 < NT2) STAGE_B2(t + 3);
        __builtin_amdgcn_s_barrier();
        asm volatile("s_waitcnt lgkmcnt(0)" ::: "memory");
        __builtin_amdgcn_sched_barrier(0);
        __builtin_amdgcn_s_setprio(1);
#pragma unroll
        for (int n = 0; n < 4; n++)
#pragma unroll
            for (int m = 0; m < 4; m++)
                acc[4 + m][n] = __builtin_amdgcn_mfma_f32_16x16x32_bf16(af[m], bf[n], acc[4 + m][n], 0, 0, 0);
        __builtin_amdgcn_s_setprio(0);
    }
#undef STAGE_A2
#undef STAGE_B2

#pragma unroll
    for (int m = 0; m < 8; m++) {
#pragma unroll
        for (int r = 0; r < 4; r++) {
            int lrow = rb * 256 + wm * 128 + m * 16 + quad * 4 + r;
            if (lrow >= L) continue;
            size_t slot = (size_t)(s + lrow);
#pragma unroll
            for (int n = 0; n < 4; n++) {
                h2[slot * D_HID + cbase + wn * 64 + n * 16 + ln] = f32_to_bf16(acc[m][n][r]);
            }
        }
    }
}

// ---------------- combine: out[t] = h2[slot0] + h2[slot1] + h2[shared] ----------------
__global__ void combine_kernel(const u16* __restrict__ h2, const int* __restrict__ inv,
                               float* __restrict__ out) {
    const int t = blockIdx.x;
    const int d = threadIdx.x * 8;
    const size_t r0 = (size_t)inv[t * 2] * D_HID + d;
    const size_t r1 = (size_t)inv[t * 2 + 1] * D_HID + d;
    const size_t r2 = (size_t)(N_ROUTED + t) * D_HID + d;
    union { uint4 v; u16 us[8]; } a, b, c;
    a.v = *(const uint4*)(h2 + r0);
    b.v = *(const uint4*)(h2 + r1);
    c.v = *(const uint4*)(h2 + r2);
    float4 lo, hi;
    lo.x = bf16_to_f32(a.us[0]) + bf16_to_f32(b.us[0]) + bf16_to_f32(c.us[0]);
    lo.y = bf16_to_f32(a.us[1]) + bf16_to_f32(b.us[1]) + bf16_to_f32(c.us[1]);
    lo.z = bf16_to_f32(a.us[2]) + bf16_to_f32(b.us[2]) + bf16_to_f32(c.us[2]);
    lo.w = bf16_to_f32(a.us[3]) + bf16_to_f32(b.us[3]) + bf16_to_f32(c.us[3]);
    hi.x = bf16_to_f32(a.us[4]) + bf16_to_f32(b.us[4]) + bf16_to_f32(c.us[4]);
    hi.y = bf16_to_f32(a.us[5]) + bf16_to_f32(b.us[5]) + bf16_to_f32(c.us[5]);
    hi.z = bf16_to_f32(a.us[6]) + bf16_to_f32(b.us[6]) + bf16_to_f32(c.us[6]);
    hi.w = bf16_to_f32(a.us[7]) + bf16_to_f32(b.us[7]) + bf16_to_f32(c.us[7]);
    float* o = out + (size_t)t * D_HID + d;
    *(float4*)o = lo;
    *(float4*)(o + 4) = hi;
}

// ---------------- launch ----------------
extern "C" void kernel_launch(void* const* d_in, const int* in_sizes, int n_in,
                              void* d_out, int out_size, void* d_ws, size_t ws_size,
                              hipStream_t stream) {
    const float* x       = (const float*)d_in[0];
    const float* W_g     = (const float*)d_in[1];
    const float* W_gate  = (const float*)d_in[2];
    const float* W_up    = (const float*)d_in[3];
    const float* W_down  = (const float*)d_in[4];
    const float* Ws_gate = (const float*)d_in[5];
    const float* Ws_up   = (const float*)d_in[6];
    const float* Ws_down = (const float*)d_in[7];
    float* out = (float*)d_out;
    char* ws = (char*)d_ws;

    u16*   xb    = (u16*)(ws + OFF_XB);
    u16*   Wg_t  = (u16*)(ws + OFF_WG);
    u16*   Wu_t  = (u16*)(ws + OFF_WU);
    u16*   Wd_t  = (u16*)(ws + OFF_WD);
    u16*   Wsg_t = (u16*)(ws + OFF_WSG);
    u16*   Wsu_t = (u16*)(ws + OFF_WSU);
    u16*   Wsd_t = (u16*)(ws + OFF_WSD);
    u16*   h     = (u16*)(ws + OFF_H);
    u16*   h2    = (u16*)(ws + OFF_H2);
    int*   rows  = (int*)(ws + OFF_ROWS);
    float* wslot = (float*)(ws + OFF_WSLOT);
    int*   seg   = (int*)(ws + OFF_SEG);
    int*   blkmap= (int*)(ws + OFF_BLK);
    int*   topi  = (int*)(ws + OFF_TOPI);
    float* topw  = (float*)(ws + OFF_TOPW);
    int*   inv   = (int*)(ws + OFF_INV);

    cvt_x_kernel<<<dim3((N_TOK * D_HID) / (256 * 8)), dim3(256), 0, stream>>>(x, xb);
    prep_gu_kernel<<<dim3(D_EXP / 64, D_HID / 64, 18), dim3(256), 0, stream>>>(
        W_gate, W_up, Ws_gate, Ws_up, Wg_t, Wu_t, Wsg_t, Wsu_t);
    prep_d_kernel<<<dim3(D_HID / 64, D_EXP / 64, 9), dim3(256), 0, stream>>>(
        W_down, Ws_down, Wd_t, Wsd_t);

    router_kernel<<<dim3(N_TOK / 4), dim3(256), 0, stream>>>(x, W_g, topi, topw);
    builder_kernel<<<dim3(1), dim3(256), 0, stream>>>(topi, topw, rows, wslot, seg, blkmap, inv);

    // 1-D grids: bid&7 = column-block = XCD (round-robin dispatch)
    gemm1_kernel<<<dim3(MAX_BLK * (D_EXP / 128)), dim3(512), 0, stream>>>(
        xb, Wg_t, Wu_t, Wsg_t, Wsu_t, rows, wslot, seg, blkmap, h);
    gemm2_kernel<<<dim3(MAX_BLK * (D_HID / 256)), dim3(512), 0, stream>>>(
        h, Wd_t, Wsd_t, seg, blkmap, h2);
    combine_kernel<<<dim3(N_TOK), dim3(256), 0, stream>>>(h2, inv, out);
}

// Round 3
// 516.430 us; speedup vs baseline: 1.0924x; 1.0218x over previous
//
#include <hip/hip_runtime.h>
#include <cstdint>
#include <cstddef>

#define N_TOK 4096
#define D_HID 2048
#define D_EXP 1024
#define NE 8
#define N_ROUTED (N_TOK * 2)
#define N_ROWS (N_ROUTED + N_TOK)   // 12288: 8192 routed slots + 4096 shared
#define MAX_BLK 112                 // >= worst-case 128-row blocks (<=104)
#define NT1 (D_HID / 32)            // 64 K-tiles (gemm1)
#define NT2 (D_EXP / 32)            // 32 K-tiles (gemm2)

typedef unsigned short u16;
typedef __bf16 bf16x8 __attribute__((ext_vector_type(8)));
typedef float f32x4 __attribute__((ext_vector_type(4)));

// ---------------- workspace layout (bytes) ----------------
constexpr size_t OFF_XB    = 0;                        // u16[N_TOK*D_HID]
constexpr size_t OFF_WG    = OFF_XB    + 16777216;     // u16[NE][D_EXP][D_HID]  (n,k)
constexpr size_t OFF_WU    = OFF_WG    + 33554432;     // u16[NE][D_EXP][D_HID]
constexpr size_t OFF_WD    = OFF_WU    + 33554432;     // u16[NE][D_HID][D_EXP]  (n,k)
constexpr size_t OFF_WSG   = OFF_WD    + 33554432;     // u16[D_EXP][D_HID]
constexpr size_t OFF_WSU   = OFF_WSG   + 4194304;      // u16[D_EXP][D_HID]
constexpr size_t OFF_WSD   = OFF_WSU   + 4194304;      // u16[D_HID][D_EXP]
constexpr size_t OFF_H     = OFF_WSD   + 4194304;      // u16[N_ROWS*D_EXP]
constexpr size_t OFF_ROWS  = OFF_H     + 25165824;     // int[N_ROWS]
constexpr size_t OFF_WSLOT = OFF_ROWS  + 49152;        // float[N_ROWS]
constexpr size_t OFF_SEG   = OFF_WSLOT + 49152;        // int[32]
constexpr size_t OFF_BLK   = OFF_SEG   + 128;          // int[192] block map
constexpr size_t OFF_TOPI  = OFF_BLK   + 768;          // int[2*N_TOK]
constexpr size_t OFF_TOPW  = OFF_TOPI  + 32768;        // float[2*N_TOK]
constexpr size_t OFF_INV   = OFF_TOPW  + 32768;        // int[2*N_TOK] token->slot
// h2 aliases Wg_t/Wu_t: dead after gemm1, stream-ordered before gemm2/combine.
constexpr size_t OFF_H2    = OFF_WG;

__device__ __forceinline__ u16 f32_to_bf16(float f) {
    union { float f; unsigned int u; } c; c.f = f;
    unsigned int u = c.u;
    return (u16)((u + 0x7FFFu + ((u >> 16) & 1u)) >> 16);
}
__device__ __forceinline__ float bf16_to_f32(u16 v) {
    union { unsigned int u; float f; } c; c.u = ((unsigned int)v) << 16;
    return c.f;
}

// async global->LDS, 16B per lane; lds dest = wave-uniform base + lane*16
__device__ __forceinline__ void gld_lds16(const u16* g, u16* l) {
    __builtin_amdgcn_global_load_lds(
        (const __attribute__((address_space(1))) void*)g,
        (__attribute__((address_space(3))) void*)l,
        16, 0, 0);
}

// ---------------- x -> bf16 ----------------
__global__ void cvt_x_kernel(const float* __restrict__ x, u16* __restrict__ xb) {
    size_t i = ((size_t)blockIdx.x * 256 + threadIdx.x) * 8;
    float4 a = *(const float4*)(x + i);
    float4 b = *(const float4*)(x + i + 4);
    union { u16 us[8]; uint4 v; } r;
    r.us[0] = f32_to_bf16(a.x); r.us[1] = f32_to_bf16(a.y);
    r.us[2] = f32_to_bf16(a.z); r.us[3] = f32_to_bf16(a.w);
    r.us[4] = f32_to_bf16(b.x); r.us[5] = f32_to_bf16(b.y);
    r.us[6] = f32_to_bf16(b.z); r.us[7] = f32_to_bf16(b.w);
    *(uint4*)(xb + i) = r.v;
}

// ---------------- weight prep: fp32 [R][C] -> bf16 [C][R], batched ----------------
__global__ void prep_gu_kernel(const float* __restrict__ Wg, const float* __restrict__ Wu,
                               const float* __restrict__ Wsg, const float* __restrict__ Wsu,
                               u16* __restrict__ Wg_t, u16* __restrict__ Wu_t,
                               u16* __restrict__ Wsg_t, u16* __restrict__ Wsu_t) {
    __shared__ float tile[64][66];
    const int z = blockIdx.z;
    const float* src; u16* dst;
    if (z < 8)        { src = Wg + (size_t)z * (D_HID * D_EXP);       dst = Wg_t + (size_t)z * (D_HID * D_EXP); }
    else if (z < 16)  { src = Wu + (size_t)(z - 8) * (D_HID * D_EXP); dst = Wu_t + (size_t)(z - 8) * (D_HID * D_EXP); }
    else if (z == 16) { src = Wsg; dst = Wsg_t; }
    else              { src = Wsu; dst = Wsu_t; }
    const int c0 = blockIdx.x * 64, r0 = blockIdx.y * 64;
    const int tid = threadIdx.x;
    const int tx = tid & 15, ty = tid >> 4;
#pragma unroll
    for (int i = 0; i < 4; i++) {
        float4 v = *(const float4*)(src + (size_t)(r0 + ty + 16 * i) * D_EXP + c0 + tx * 4);
        tile[ty + 16 * i][tx * 4 + 0] = v.x;
        tile[ty + 16 * i][tx * 4 + 1] = v.y;
        tile[ty + 16 * i][tx * 4 + 2] = v.z;
        tile[ty + 16 * i][tx * 4 + 3] = v.w;
    }
    __syncthreads();
    const int kx = tid & 7, cy = tid >> 3;
#pragma unroll
    for (int j = 0; j < 2; j++) {
        int n = cy + 32 * j;
        union { u16 us[8]; uint4 v; } r;
#pragma unroll
        for (int m = 0; m < 8; m++) r.us[m] = f32_to_bf16(tile[kx * 8 + m][n]);
        *(uint4*)(dst + (size_t)(c0 + n) * D_HID + r0 + kx * 8) = r.v;
    }
}

__global__ void prep_d_kernel(const float* __restrict__ Wd, const float* __restrict__ Wsd,
                              u16* __restrict__ Wd_t, u16* __restrict__ Wsd_t) {
    __shared__ float tile[64][66];
    const int z = blockIdx.z;
    const float* src; u16* dst;
    if (z < 8) { src = Wd + (size_t)z * (D_EXP * D_HID); dst = Wd_t + (size_t)z * (D_EXP * D_HID); }
    else       { src = Wsd; dst = Wsd_t; }
    const int c0 = blockIdx.x * 64, r0 = blockIdx.y * 64;
    const int tid = threadIdx.x;
    const int tx = tid & 15, ty = tid >> 4;
#pragma unroll
    for (int i = 0; i < 4; i++) {
        float4 v = *(const float4*)(src + (size_t)(r0 + ty + 16 * i) * D_HID + c0 + tx * 4);
        tile[ty + 16 * i][tx * 4 + 0] = v.x;
        tile[ty + 16 * i][tx * 4 + 1] = v.y;
        tile[ty + 16 * i][tx * 4 + 2] = v.z;
        tile[ty + 16 * i][tx * 4 + 3] = v.w;
    }
    __syncthreads();
    const int kx = tid & 7, cy = tid >> 3;
#pragma unroll
    for (int j = 0; j < 2; j++) {
        int n = cy + 32 * j;
        union { u16 us[8]; uint4 v; } r;
#pragma unroll
        for (int m = 0; m < 8; m++) r.us[m] = f32_to_bf16(tile[kx * 8 + m][n]);
        *(uint4*)(dst + (size_t)(c0 + n) * D_EXP + r0 + kx * 8) = r.v;
    }
}

// ---------------- router: softmax + top2 ----------------
__global__ void router_kernel(const float* __restrict__ x, const float* __restrict__ Wg,
                              int* __restrict__ topi, float* __restrict__ topw) {
    const int wave = threadIdx.x >> 6, lane = threadIdx.x & 63;
    const int t = blockIdx.x * 4 + wave;
    const float* xr = x + (size_t)t * D_HID;
    float acc[8] = {0.f, 0.f, 0.f, 0.f, 0.f, 0.f, 0.f, 0.f};
    for (int k = lane; k < D_HID; k += 64) {
        float xv = xr[k];
        float4 w0 = *(const float4*)(Wg + k * 8);
        float4 w1 = *(const float4*)(Wg + k * 8 + 4);
        acc[0] += xv * w0.x; acc[1] += xv * w0.y; acc[2] += xv * w0.z; acc[3] += xv * w0.w;
        acc[4] += xv * w1.x; acc[5] += xv * w1.y; acc[6] += xv * w1.z; acc[7] += xv * w1.w;
    }
#pragma unroll
    for (int e = 0; e < 8; e++)
#pragma unroll
        for (int off = 32; off > 0; off >>= 1)
            acc[e] += __shfl_xor(acc[e], off);
    if (lane == 0) {
        float mx = acc[0];
#pragma unroll
        for (int e = 1; e < 8; e++) mx = fmaxf(mx, acc[e]);
        float p[8], sum = 0.f;
#pragma unroll
        for (int e = 0; e < 8; e++) { p[e] = __expf(acc[e] - mx); sum += p[e]; }
        int i0 = 0; float b0 = p[0];
#pragma unroll
        for (int e = 1; e < 8; e++) if (p[e] > b0) { b0 = p[e]; i0 = e; }
        int i1 = -1; float b1 = -1.f;
#pragma unroll
        for (int e = 0; e < 8; e++) if (e != i0 && p[e] > b1) { b1 = p[e]; i1 = e; }
        float inv = 1.f / sum;
        topi[t * 2] = i0;  topi[t * 2 + 1] = i1;
        topw[t * 2] = b0 * inv; topw[t * 2 + 1] = b1 * inv;
    }
}

// ---------------- build expert segments + block map (128-row blocks) ----------------
__global__ void builder_kernel(const int* __restrict__ topi, const float* __restrict__ topw,
                               int* __restrict__ rows, float* __restrict__ wslot,
                               int* __restrict__ seg, int* __restrict__ blkmap,
                               int* __restrict__ inv) {
    __shared__ int cnt[8], offs[8];
    const int tid = threadIdx.x;
    if (tid < 8) cnt[tid] = 0;
    __syncthreads();
    for (int i = tid; i < N_TOK * 2; i += 256) atomicAdd(&cnt[topi[i]], 1);
    __syncthreads();
    if (tid == 0) {
        int run = 0;
        for (int e = 0; e < 8; e++) {
            offs[e] = run; seg[e] = run; seg[16 + e] = cnt[e]; run += cnt[e];
        }
        seg[8] = N_ROUTED; seg[16 + 8] = N_TOK;
        int nb = 0;
        for (int e = 0; e < 9; e++) {
            int L = (e < 8) ? cnt[e] : N_TOK;
            for (int rb = 0; rb * 128 < L; rb++) blkmap[nb++] = (e << 8) | rb;
        }
        seg[10] = nb;
    }
    __syncthreads();
    for (int i = tid; i < N_TOK * 2; i += 256) {
        int e = topi[i];
        int p = atomicAdd(&offs[e], 1);
        rows[p] = i >> 1;
        wslot[p] = topw[i];
        inv[i] = p;
    }
    for (int t = tid; t < N_TOK; t += 256) {
        rows[N_ROUTED + t] = t;
        wslot[N_ROUTED + t] = 1.0f;
    }
}

// =====================================================================
// GEMM1: gathered X @ {W_gate, W_up} + silu*up*w -> h (bf16)
// R3: BM=128, 4 waves (2m x 2n), ring-3 LDS (74KB) -> 2 blocks/CU so
// stalls decorrelate across independent blocks (TLP). Same verified
// swizzle/staging/phase skeleton as R2, counted vmcnt(6).
// per buffer (12288 u16 = 24KB): A[128][32]@0, Bg[128][32]@4096, Bu@8192
// =====================================================================
__global__ __launch_bounds__(256, 2)
void gemm1_kernel(const u16* __restrict__ xb,
                  const u16* __restrict__ Wg_t, const u16* __restrict__ Wu_t,
                  const u16* __restrict__ Wsg_t, const u16* __restrict__ Wsu_t,
                  const int* __restrict__ rows, const float* __restrict__ wslot,
                  const int* __restrict__ seg, const int* __restrict__ blkmap,
                  u16* __restrict__ h) {
    __shared__ u16 lds[3][12288];
    __shared__ int tok_s[128];
    const int f = blockIdx.x;
    const int iy = f & 7, ix = f >> 3;   // iy -> XCD (round-robin dispatch)
    if (ix >= seg[10]) return;
    const int code = blkmap[ix];
    const int e = code >> 8, rb = code & 255;
    const int s = seg[e], L = seg[e + 16];
    const u16* Bg = (e < NE) ? Wg_t + (size_t)e * D_EXP * D_HID : Wsg_t;
    const u16* Bu = (e < NE) ? Wu_t + (size_t)e * D_EXP * D_HID : Wsu_t;
    const int cbase = iy * 128;
    const int tid = threadIdx.x;
    if (tid < 128) {
        int lr = rb * 128 + tid;
        tok_s[tid] = rows[s + (lr < L ? lr : 0)];
    }
    __syncthreads();

    const int l = tid & 63, w = tid >> 6;   // w in 0..3
    // staging: lane l stages row (w*16 + l>>2), phys chunk (l&3),
    // from global chunk (l&3)^((l>>3)&3)  [phys p holds chunk p^((row>>1)&3)]
    const int rl = l >> 2;
    const int cg = (l & 3) ^ ((l >> 3) & 3);
    const int rowS = w * 16 + rl;
    const u16* gA0  = xb + (size_t)tok_s[rowS] * D_HID + cg * 8;
    const u16* gA1  = xb + (size_t)tok_s[64 + rowS] * D_HID + cg * 8;
    const u16* gBg0 = Bg + (size_t)(cbase + rowS) * D_HID + cg * 8;
    const u16* gBg1 = Bg + (size_t)(cbase + 64 + rowS) * D_HID + cg * 8;
    const u16* gBu0 = Bu + (size_t)(cbase + rowS) * D_HID + cg * 8;
    const u16* gBu1 = Bu + (size_t)(cbase + 64 + rowS) * D_HID + cg * 8;
    const int wbase = w * 512;

    const int wm = w & 1, wn = w >> 1;           // wave tile: rows wm*64, cols wn*64
    const int ln = l & 15, quad = l >> 4;
    const int pch = (quad ^ ((ln >> 1) & 3)) * 8;       // swizzled 16B chunk within row
    const int aoff = (wm * 64 + ln) * 32 + pch;         // + m*512
    const int goff = 4096 + (wn * 64 + ln) * 32 + pch;  // + n*512
    const int uoff = 8192 + (wn * 64 + ln) * 32 + pch;  // + n*512

    f32x4 accg[4][4], accu[4][4];
    const f32x4 zero = {0.f, 0.f, 0.f, 0.f};
#pragma unroll
    for (int i = 0; i < 4; i++)
#pragma unroll
        for (int j = 0; j < 4; j++) { accg[i][j] = zero; accu[i][j] = zero; }

#define STAGE_A1(t, d) { \
        gld_lds16(gA0 + (t) * 32, (d) + wbase); \
        gld_lds16(gA1 + (t) * 32, (d) + 2048 + wbase); }
#define STAGE_B1(t, d) { \
        gld_lds16(gBg0 + (t) * 32, (d) + 4096 + wbase); \
        gld_lds16(gBg1 + (t) * 32, (d) + 6144 + wbase); \
        gld_lds16(gBu0 + (t) * 32, (d) + 8192 + wbase); \
        gld_lds16(gBu1 + (t) * 32, (d) + 10240 + wbase); }

    // prologue: 2 tiles in flight
    STAGE_A1(0, &lds[0][0]); STAGE_B1(0, &lds[0][0]);
    STAGE_A1(1, &lds[1][0]); STAGE_B1(1, &lds[1][0]);

    int cur = 0;
#pragma unroll 1
    for (int t = 0; t < NT1; ++t) {
        // own tile-t loads landed (tile t+1's 6 may remain in flight)
        if (t < NT1 - 1) asm volatile("s_waitcnt vmcnt(6)" ::: "memory");
        else             asm volatile("s_waitcnt vmcnt(0)" ::: "memory");
        __builtin_amdgcn_s_barrier();           // buf[cur] ready block-wide; buf[(t+2)%3] free
        __builtin_amdgcn_sched_barrier(0);
        const u16* bufp = &lds[cur][0];
        int stb = cur + 2; if (stb >= 3) stb -= 3;
        u16* sdst = &lds[stb][0];
        const bool do_stage = (t + 2 < NT1);
        bf16x8 af[2], bg[4], bu[4];
        // ---- P0: m=0,1; B read once for whole tile ----
#pragma unroll
        for (int m = 0; m < 2; m++) af[m] = *(const bf16x8*)(bufp + aoff + m * 512);
#pragma unroll
        for (int n = 0; n < 4; n++) {
            bg[n] = *(const bf16x8*)(bufp + goff + n * 512);
            bu[n] = *(const bf16x8*)(bufp + uoff + n * 512);
        }
        if (do_stage) STAGE_A1(t + 2, sdst);
        __builtin_amdgcn_s_barrier();
        asm volatile("s_waitcnt lgkmcnt(0)" ::: "memory");
        __builtin_amdgcn_sched_barrier(0);
        __builtin_amdgcn_s_setprio(1);
#pragma unroll
        for (int n = 0; n < 4; n++)
#pragma unroll
            for (int m = 0; m < 2; m++) {
                accg[m][n] = __builtin_amdgcn_mfma_f32_16x16x32_bf16(af[m], bg[n], accg[m][n], 0, 0, 0);
                accu[m][n] = __builtin_amdgcn_mfma_f32_16x16x32_bf16(af[m], bu[n], accu[m][n], 0, 0, 0);
            }
        __builtin_amdgcn_s_setprio(0);
        // ---- P1: m=2,3; B kept in regs ----
#pragma unroll
        for (int m = 0; m < 2; m++) af[m] = *(const bf16x8*)(bufp + aoff + (2 + m) * 512);
        if (do_stage) STAGE_B1(t + 2, sdst);
        __builtin_amdgcn_s_barrier();
        asm volatile("s_waitcnt lgkmcnt(0)" ::: "memory");
        __builtin_amdgcn_sched_barrier(0);
        __builtin_amdgcn_s_setprio(1);
#pragma unroll
        for (int n = 0; n < 4; n++)
#pragma unroll
            for (int m = 0; m < 2; m++) {
                accg[2 + m][n] = __builtin_amdgcn_mfma_f32_16x16x32_bf16(af[m], bg[n], accg[2 + m][n], 0, 0, 0);
                accu[2 + m][n] = __builtin_amdgcn_mfma_f32_16x16x32_bf16(af[m], bu[n], accu[2 + m][n], 0, 0, 0);
            }
        __builtin_amdgcn_s_setprio(0);
        cur++; if (cur >= 3) cur = 0;
    }
#undef STAGE_A1
#undef STAGE_B1

    // epilogue: silu(g)*u*w -> h
#pragma unroll
    for (int m = 0; m < 4; m++) {
#pragma unroll
        for (int r = 0; r < 4; r++) {
            int lrow = rb * 128 + wm * 64 + m * 16 + quad * 4 + r;
            if (lrow >= L) continue;
            int pos = s + lrow;
            float wgt = wslot[pos];
#pragma unroll
            for (int n = 0; n < 4; n++) {
                float g = accg[m][n][r];
                float u = accu[m][n][r];
                float hv = (g / (1.f + __expf(-g))) * u * wgt;
                h[(size_t)pos * D_EXP + cbase + wn * 64 + n * 16 + ln] = f32_to_bf16(hv);
            }
        }
    }
}

// =====================================================================
// GEMM2: h @ W_down -> h2 (bf16 per-slot), same R3 geometry.
// BM=128, BN=256, 4 waves (2m x 2n), ring-3.
// per buffer: A[128][32]@0, B[256][32]@4096 (u16 units)
// =====================================================================
__global__ __launch_bounds__(256, 2)
void gemm2_kernel(const u16* __restrict__ h,
                  const u16* __restrict__ Wd_t, const u16* __restrict__ Wsd_t,
                  const int* __restrict__ seg, const int* __restrict__ blkmap,
                  u16* __restrict__ h2) {
    __shared__ u16 lds[3][12288];
    const int f = blockIdx.x;
    const int iy = f & 7, ix = f >> 3;   // iy -> XCD
    if (ix >= seg[10]) return;
    const int code = blkmap[ix];
    const int e = code >> 8, rb = code & 255;
    const int s = seg[e], L = seg[e + 16];
    const u16* B = (e < NE) ? Wd_t + (size_t)e * D_HID * D_EXP : Wsd_t;  // [N=2048][K=1024]
    const int cbase = iy * 256;
    const int tid = threadIdx.x;

    const int l = tid & 63, w = tid >> 6;
    const int rl = l >> 2;
    const int cg = (l & 3) ^ ((l >> 3) & 3);
    const int rowS = w * 16 + rl;
    const u16* gA0 = h + (size_t)(s + rb * 128 + rowS) * D_EXP + cg * 8;
    const u16* gA1 = gA0 + (size_t)64 * D_EXP;
    const u16* gB0 = B + (size_t)(cbase + rowS) * D_EXP + cg * 8;
    const u16* gB1 = gB0 + (size_t)64 * D_EXP;
    const u16* gB2 = gB0 + (size_t)128 * D_EXP;
    const u16* gB3 = gB0 + (size_t)192 * D_EXP;
    const int wbase = w * 512;

    const int wm = w & 1, wn = w >> 1;           // wave tile: rows wm*64, cols wn*128
    const int ln = l & 15, quad = l >> 4;
    const int pch = (quad ^ ((ln >> 1) & 3)) * 8;
    const int aoff = (wm * 64 + ln) * 32 + pch;          // + m*512
    const int boff = 4096 + (wn * 128 + ln) * 32 + pch;  // + n*512

    f32x4 acc[4][8];
    const f32x4 zero = {0.f, 0.f, 0.f, 0.f};
#pragma unroll
    for (int i = 0; i < 4; i++)
#pragma unroll
        for (int j = 0; j < 8; j++) acc[i][j] = zero;

#define STAGE_A2(t, d) { \
        gld_lds16(gA0 + (t) * 32, (d) + wbase); \
        gld_lds16(gA1 + (t) * 32, (d) + 2048 + wbase); }
#define STAGE_B2(t, d) { \
        gld_lds16(gB0 + (t) * 32, (d) + 4096 + wbase); \
        gld_lds16(gB1 + (t) * 32, (d) + 6144 + wbase); \
        gld_lds16(gB2 + (t) * 32, (d) + 8192 + wbase); \
        gld_lds16(gB3 + (t) * 32, (d) + 10240 + wbase); }

    STAGE_A2(0, &lds[0][0]); STAGE_B2(0, &lds[0][0]);
    STAGE_A2(1, &lds[1][0]); STAGE_B2(1, &lds[1][0]);

    int cur = 0;
#pragma unroll 1
    for (int t = 0; t < NT2; ++t) {
        if (t < NT2 - 1) asm volatile("s_waitcnt vmcnt(6)" ::: "memory");
        else             asm volatile("s_waitcnt vmcnt(0)" ::: "memory");
        __builtin_amdgcn_s_barrier();
        __builtin_amdgcn_sched_barrier(0);
        const u16* bufp = &lds[cur][0];
        int stb = cur + 2; if (stb >= 3) stb -= 3;
        u16* sdst = &lds[stb][0];
        const bool do_stage = (t + 2 < NT2);
        bf16x8 af[2], bf[8];
        // ---- P0: m=0,1; B read once for whole tile ----
#pragma unroll
        for (int m = 0; m < 2; m++) af[m] = *(const bf16x8*)(bufp + aoff + m * 512);
#pragma unroll
        for (int n = 0; n < 8; n++) bf[n] = *(const bf16x8*)(bufp + boff + n * 512);
        if (do_stage) STAGE_A2(t + 2, sdst);
        __builtin_amdgcn_s_barrier();
        asm volatile("s_waitcnt lgkmcnt(0)" ::: "memory");
        __builtin_amdgcn_sched_barrier(0);
        __builtin_amdgcn_s_setprio(1);
#pragma unroll
        for (int n = 0; n < 8; n++)
#pragma unroll
            for (int m = 0; m < 2; m++)
                acc[m][n] = __builtin_amdgcn_mfma_f32_16x16x32_bf16(af[m], bf[n], acc[m][n], 0, 0, 0);
        __builtin_amdgcn_s_setprio(0);
        // ---- P1: m=2,3 ----
#pragma unroll
        for (int m = 0; m < 2; m++) af[m] = *(const bf16x8*)(bufp + aoff + (2 + m) * 512);
        if (do_stage) STAGE_B2(t + 2, sdst);
        __builtin_amdgcn_s_barrier();
        asm volatile("s_waitcnt lgkmcnt(0)" ::: "memory");
        __builtin_amdgcn_sched_barrier(0);
        __builtin_amdgcn_s_setprio(1);
#pragma unroll
        for (int n = 0; n < 8; n++)
#pragma unroll
            for (int m = 0; m < 2; m++)
                acc[2 + m][n] = __builtin_amdgcn_mfma_f32_16x16x32_bf16(af[m], bf[n], acc[2 + m][n], 0, 0, 0);
        __builtin_amdgcn_s_setprio(0);
        cur++; if (cur >= 3) cur = 0;
    }
#undef STAGE_A2
#undef STAGE_B2

#pragma unroll
    for (int m = 0; m < 4; m++) {
#pragma unroll
        for (int r = 0; r < 4; r++) {
            int lrow = rb * 128 + wm * 64 + m * 16 + quad * 4 + r;
            if (lrow >= L) continue;
            size_t slot = (size_t)(s + lrow);
#pragma unroll
            for (int n = 0; n < 8; n++) {
                h2[slot * D_HID + cbase + wn * 128 + n * 16 + ln] = f32_to_bf16(acc[m][n][r]);
            }
        }
    }
}

// ---------------- combine: out[t] = h2[slot0] + h2[slot1] + h2[shared] ----------------
__global__ void combine_kernel(const u16* __restrict__ h2, const int* __restrict__ inv,
                               float* __restrict__ out) {
    const int t = blockIdx.x;
    const int d = threadIdx.x * 8;
    const size_t r0 = (size_t)inv[t * 2] * D_HID + d;
    const size_t r1 = (size_t)inv[t * 2 + 1] * D_HID + d;
    const size_t r2 = (size_t)(N_ROUTED + t) * D_HID + d;
    union { uint4 v; u16 us[8]; } a, b, c;
    a.v = *(const uint4*)(h2 + r0);
    b.v = *(const uint4*)(h2 + r1);
    c.v = *(const uint4*)(h2 + r2);
    float4 lo, hi;
    lo.x = bf16_to_f32(a.us[0]) + bf16_to_f32(b.us[0]) + bf16_to_f32(c.us[0]);
    lo.y = bf16_to_f32(a.us[1]) + bf16_to_f32(b.us[1]) + bf16_to_f32(c.us[1]);
    lo.z = bf16_to_f32(a.us[2]) + bf16_to_f32(b.us[2]) + bf16_to_f32(c.us[2]);
    lo.w = bf16_to_f32(a.us[3]) + bf16_to_f32(b.us[3]) + bf16_to_f32(c.us[3]);
    hi.x = bf16_to_f32(a.us[4]) + bf16_to_f32(b.us[4]) + bf16_to_f32(c.us[4]);
    hi.y = bf16_to_f32(a.us[5]) + bf16_to_f32(b.us[5]) + bf16_to_f32(c.us[5]);
    hi.z = bf16_to_f32(a.us[6]) + bf16_to_f32(b.us[6]) + bf16_to_f32(c.us[6]);
    hi.w = bf16_to_f32(a.us[7]) + bf16_to_f32(b.us[7]) + bf16_to_f32(c.us[7]);
    float* o = out + (size_t)t * D_HID + d;
    *(float4*)o = lo;
    *(float4*)(o + 4) = hi;
}

// ---------------- launch ----------------
extern "C" void kernel_launch(void* const* d_in, const int* in_sizes, int n_in,
                              void* d_out, int out_size, void* d_ws, size_t ws_size,
                              hipStream_t stream) {
    const float* x       = (const float*)d_in[0];
    const float* W_g     = (const float*)d_in[1];
    const float* W_gate  = (const float*)d_in[2];
    const float* W_up    = (const float*)d_in[3];
    const float* W_down  = (const float*)d_in[4];
    const float* Ws_gate = (const float*)d_in[5];
    const float* Ws_up   = (const float*)d_in[6];
    const float* Ws_down = (const float*)d_in[7];
    float* out = (float*)d_out;
    char* ws = (char*)d_ws;

    u16*   xb    = (u16*)(ws + OFF_XB);
    u16*   Wg_t  = (u16*)(ws + OFF_WG);
    u16*   Wu_t  = (u16*)(ws + OFF_WU);
    u16*   Wd_t  = (u16*)(ws + OFF_WD);
    u16*   Wsg_t = (u16*)(ws + OFF_WSG);
    u16*   Wsu_t = (u16*)(ws + OFF_WSU);
    u16*   Wsd_t = (u16*)(ws + OFF_WSD);
    u16*   h     = (u16*)(ws + OFF_H);
    u16*   h2    = (u16*)(ws + OFF_H2);
    int*   rows  = (int*)(ws + OFF_ROWS);
    float* wslot = (float*)(ws + OFF_WSLOT);
    int*   seg   = (int*)(ws + OFF_SEG);
    int*   blkmap= (int*)(ws + OFF_BLK);
    int*   topi  = (int*)(ws + OFF_TOPI);
    float* topw  = (float*)(ws + OFF_TOPW);
    int*   inv   = (int*)(ws + OFF_INV);

    cvt_x_kernel<<<dim3((N_TOK * D_HID) / (256 * 8)), dim3(256), 0, stream>>>(x, xb);
    prep_gu_kernel<<<dim3(D_EXP / 64, D_HID / 64, 18), dim3(256), 0, stream>>>(
        W_gate, W_up, Ws_gate, Ws_up, Wg_t, Wu_t, Wsg_t, Wsu_t);
    prep_d_kernel<<<dim3(D_HID / 64, D_EXP / 64, 9), dim3(256), 0, stream>>>(
        W_down, Ws_down, Wd_t, Wsd_t);

    router_kernel<<<dim3(N_TOK / 4), dim3(256), 0, stream>>>(x, W_g, topi, topw);
    builder_kernel<<<dim3(1), dim3(256), 0, stream>>>(topi, topw, rows, wslot, seg, blkmap, inv);

    // 1-D grids: bid&7 = column-block = XCD (round-robin dispatch)
    gemm1_kernel<<<dim3(MAX_BLK * 8), dim3(256), 0, stream>>>(
        xb, Wg_t, Wu_t, Wsg_t, Wsu_t, rows, wslot, seg, blkmap, h);
    gemm2_kernel<<<dim3(MAX_BLK * 8), dim3(256), 0, stream>>>(
        h, Wd_t, Wsd_t, seg, blkmap, h2);
    combine_kernel<<<dim3(N_TOK), dim3(256), 0, stream>>>(h2, inv, out);
}